// Round 8
// baseline (2085.035 us; speedup 1.0000x reference)
//
#include <hip/hip_runtime.h>
#include <math.h>

#define BB 16
#define NN 512
#define TT 32
#define CC 128
#define RR 32
#define DD 64

// fp32 Q/K handoff (module .bss; fully rewritten by k1 before k2f reads)
__device__ float g_Q[BB * NN * DD];
__device__ float g_K[BB * NN * DD];

// numpy npyv(AVX512) einsum contig-two dot emulation:
// 16-lane FMA single accumulator over ascending 16-blocks,
// then the _mm512_reduce_add_ps combine tree. All ops rounding-locked.
__device__ __forceinline__ float dot_np16(const float* __restrict__ a,
                                          const float* __restrict__ b, int n) {
    float lane[16];
#pragma unroll
    for (int l = 0; l < 16; ++l) lane[l] = 0.0f;
    for (int i = 0; i < n; i += 16) {
#pragma unroll
        for (int l = 0; l < 16; ++l)
            lane[l] = __fmaf_rn(a[i + l], b[i + l], lane[l]);
    }
    float m[8], p[4];
#pragma unroll
    for (int i = 0; i < 8; ++i) m[i] = __fadd_rn(lane[i], lane[i + 8]);
#pragma unroll
    for (int i = 0; i < 4; ++i) p[i] = __fadd_rn(m[i], m[i + 4]);
    float q0 = __fadd_rn(p[0], p[2]);
    float q1 = __fadd_rn(p[1], p[3]);
    return __fadd_rn(q0, q1);
}

#define XP 132   // padded row stride for 128-wide LDS tiles (conflict-free)

// ------------- Kernel 1: per-(b,n) pipeline -> Q,K (fp32-faithful) -----------
__global__ __launch_bounds__(256, 4) void k1(const float* __restrict__ x,
        const float* __restrict__ Ws, const float* __restrict__ Wphi,
        const float* __restrict__ b_phi, const float* __restrict__ Wmu,
        const float* __restrict__ b_mu, const float* __restrict__ WQ,
        const float* __restrict__ WK)
{
    __shared__ float Xs[TT * XP];     // 16.9 KB, padded
    __shared__ float Wss[RR * XP];    // 16.9 KB, padded (staged Ws)
    __shared__ float zta[TT * 33];    // 4.2 KB, padded
    __shared__ float xc[CC];          // avg, later X_c
    __shared__ float wsh[CC];
    __shared__ float zca[RR];
    __shared__ float lg[TT];
    __shared__ float alpha[TT];

    const int tid = threadIdx.x;
    const int bn = blockIdx.x;
    const float* xb = x + (long long)bn * (TT * CC);

    // coalesced float4 staging of X and Ws into padded LDS
#pragma unroll
    for (int k = 0; k < 4; ++k) {
        int idx = tid + (k << 8);          // float4 index 0..1023
        int t  = idx >> 5;
        int c4 = (idx & 31) << 2;
        *(float4*)&Xs[t * XP + c4]  = ((const float4*)xb)[idx];
        *(float4*)&Wss[t * XP + c4] = ((const float4*)Ws)[idx];
    }
    __syncthreads();

    // avg = np.mean over t: numpy pairwise 8-accumulator pattern, /32
    if (tid < CC) {
        float r[8];
#pragma unroll
        for (int j = 0; j < 8; ++j) r[j] = Xs[j * XP + tid];
#pragma unroll
        for (int i = 8; i < 32; i += 8)
#pragma unroll
            for (int j = 0; j < 8; ++j) r[j] = __fadd_rn(r[j], Xs[(i + j) * XP + tid]);
        float s = __fadd_rn(__fadd_rn(__fadd_rn(r[0], r[1]), __fadd_rn(r[2], r[3])),
                            __fadd_rn(__fadd_rn(r[4], r[5]), __fadd_rn(r[6], r[7])));
        xc[tid] = s / 32.0f;               // xc holds avg for now
    }
    __syncthreads();

    // z_ca = relu(einsum('c,rc->r', avg, Ws))   [LDS b-operand, conflict-free]
    if (tid < RR) {
        float lane[16];
#pragma unroll
        for (int l = 0; l < 16; ++l) lane[l] = 0.0f;
        const float* wr = &Wss[tid * XP];
        for (int i = 0; i < CC; i += 16)
#pragma unroll
            for (int l = 0; l < 16; ++l)
                lane[l] = __fmaf_rn(xc[i + l], wr[i + l], lane[l]);
        float m[8], p[4];
#pragma unroll
        for (int i = 0; i < 8; ++i) m[i] = __fadd_rn(lane[i], lane[i + 8]);
#pragma unroll
        for (int i = 0; i < 4; ++i) p[i] = __fadd_rn(m[i], m[i + 4]);
        float q0 = __fadd_rn(p[0], p[2]), q1 = __fadd_rn(p[1], p[3]);
        zca[tid] = fmaxf(__fadd_rn(q0, q1), 0.0f);
    }
    __syncthreads();

    // w = sigmoid(einsum('r,cr->c', zca, Wphi) + b_phi)
    if (tid < CC) {
        float t = __fadd_rn(dot_np16(zca, Wphi + tid * RR, RR), b_phi[tid]);
        wsh[tid] = 1.0f / (1.0f + expf(-t));
    }
    __syncthreads();

    // z_ta = relu(einsum('tc,rc->tr', X_hat, Ws)), X_hat inlined as
    // __fmul_rn(Xs,wsh) (bitwise identical to materialized X_hat)
#pragma unroll
    for (int k = 0; k < 4; ++k) {
        int i = tid + (k << 8);
        int t = i >> 5, r = i & 31;
        const float* xr = &Xs[t * XP];
        const float* wr = &Wss[r * XP];
        float lane[16];
#pragma unroll
        for (int l = 0; l < 16; ++l) lane[l] = 0.0f;
        for (int c = 0; c < CC; c += 16)
#pragma unroll
            for (int l = 0; l < 16; ++l)
                lane[l] = __fmaf_rn(__fmul_rn(xr[c + l], wsh[c + l]), wr[c + l], lane[l]);
        float m[8], p[4];
#pragma unroll
        for (int i2 = 0; i2 < 8; ++i2) m[i2] = __fadd_rn(lane[i2], lane[i2 + 8]);
#pragma unroll
        for (int i2 = 0; i2 < 4; ++i2) p[i2] = __fadd_rn(m[i2], m[i2 + 4]);
        float q0 = __fadd_rn(p[0], p[2]), q1 = __fadd_rn(p[1], p[3]);
        zta[t * 33 + r] = fmaxf(__fadd_rn(q0, q1), 0.0f);
    }
    __syncthreads();

    // logits
    if (tid < TT) lg[tid] = __fadd_rn(dot_np16(&zta[tid * 33], Wmu, RR), b_mu[0]);
    __syncthreads();

    // softmax over t (max exact; pairwise 8-acc sum like np)
    if (tid == 0) {
        float m = lg[0];
        for (int t = 1; t < TT; ++t) m = fmaxf(m, lg[t]);
        float e[TT];
        for (int t = 0; t < TT; ++t) e[t] = expf(__fsub_rn(lg[t], m));
        float r[8];
#pragma unroll
        for (int j = 0; j < 8; ++j) r[j] = e[j];
#pragma unroll
        for (int i = 8; i < 32; i += 8)
#pragma unroll
            for (int j = 0; j < 8; ++j) r[j] = __fadd_rn(r[j], e[i + j]);
        float s = __fadd_rn(__fadd_rn(__fadd_rn(r[0], r[1]), __fadd_rn(r[2], r[3])),
                            __fadd_rn(__fadd_rn(r[4], r[5]), __fadd_rn(r[6], r[7])));
        for (int t = 0; t < TT; ++t) alpha[t] = e[t] / s;
    }
    __syncthreads();

    // X_c = einsum('t,tc->c', alpha, X_hat): sequential FMA, X_hat inlined
    if (tid < CC) {
        float s = 0.0f;
        for (int t = 0; t < TT; ++t)
            s = __fmaf_rn(alpha[t], __fmul_rn(Xs[t * XP + tid], wsh[tid]), s);
        xc[tid] = s;
    }
    __syncthreads();

    // Q, K projections
    if (tid < 128) {
        int isK = tid >> 6, d = tid & 63;
        const float* Wr = (isK ? WK : WQ) + d * CC;
        float s = dot_np16(xc, Wr, CC);
        if (isK) g_K[bn * DD + d] = s;
        else     g_Q[bn * DD + d] = s;
    }
}

// ------------- Kernel 2: E rows (np-order fp32) + sigmoid-domain top-8 -------
__device__ __forceinline__ void cxf(float& a, float& b) {
    float mx = fmaxf(a, b), mn = fminf(a, b);
    a = mx; b = mn;
}

__global__ __launch_bounds__(256) void k2f(float* __restrict__ out)
{
    __shared__ float Qs[16][64];
    __shared__ float Kch[64][65];    // one 64-column chunk of the 512-row matrix

    const int tid = threadIdx.x;
    const int gid = blockIdx.x;
    const int dir = gid & 1;
    const int b   = (gid >> 1) & 15;
    const int grp = gid >> 5;                 // 0..31
    const int row_base = grp << 4;

    const float* Qrow = dir ? g_K : g_Q;      // backward: rows come from K
    const float* Mat  = dir ? g_Q : g_K;
    float* outp = out + (long long)dir * BB * NN * NN;

    for (int k = 0; k < 4; ++k) {
        int idx = tid + (k << 8);
        Qs[idx >> 6][idx & 63] =
            Qrow[(long long)(b * NN + row_base + (idx >> 6)) * DD + (idx & 63)];
    }

    const int l = tid & 63, w = tid >> 6, wrow = w << 2;
    float A[4][8];

#pragma unroll
    for (int j = 0; j < 8; ++j) {             // 8 column chunks of 64
        __syncthreads();                       // covers Qs on j==0, Kch reuse after
        for (int k = 0; k < 16; ++k) {
            int idx = tid + (k << 8);
            int row = idx >> 6, d = idx & 63;
            Kch[row][d] = Mat[(long long)(b * NN + (j << 6) + row) * DD + d];
        }
        __syncthreads();
#pragma unroll
        for (int r = 0; r < 4; ++r) {
            float e = dot_np16(Qs[wrow + r], Kch[l], DD);
            e = e / 8.0f;                      // scale = sqrt(64), exact
            A[r][j] = 1.0f / (1.0f + expf(-e));  // select in sigmoid domain
        }
    }

    const long long obase = (long long)(b * NN + row_base + wrow) * NN;

#pragma unroll
    for (int r = 0; r < 4; ++r) {
        float L[8];
#pragma unroll
        for (int j = 0; j < 8; ++j) L[j] = A[r][j];

        // Batcher odd-even merge sort, 8 elems, descending
        cxf(L[0],L[1]); cxf(L[2],L[3]); cxf(L[4],L[5]); cxf(L[6],L[7]);
        cxf(L[0],L[2]); cxf(L[1],L[3]); cxf(L[4],L[6]); cxf(L[5],L[7]);
        cxf(L[1],L[2]); cxf(L[5],L[6]);
        cxf(L[0],L[4]); cxf(L[1],L[5]); cxf(L[2],L[6]); cxf(L[3],L[7]);
        cxf(L[2],L[4]); cxf(L[3],L[5]);
        cxf(L[1],L[2]); cxf(L[3],L[4]); cxf(L[5],L[6]);

        // 64-lane butterfly merge: global top-8 of the row in every lane
#pragma unroll
        for (int mask = 1; mask < 64; mask <<= 1) {
            float Pr[8], M[8];
#pragma unroll
            for (int j = 0; j < 8; ++j) Pr[j] = __shfl_xor(L[j], mask, 64);
#pragma unroll
            for (int j = 0; j < 8; ++j) M[j] = fmaxf(L[j], Pr[7 - j]);
            cxf(M[0],M[4]); cxf(M[1],M[5]); cxf(M[2],M[6]); cxf(M[3],M[7]);
            cxf(M[0],M[2]); cxf(M[1],M[3]); cxf(M[4],M[6]); cxf(M[5],M[7]);
            cxf(M[0],M[1]); cxf(M[2],M[3]); cxf(M[4],M[5]); cxf(M[6],M[7]);
#pragma unroll
            for (int j = 0; j < 8; ++j) L[j] = M[j];
        }
        const float kth = L[7];

        float* orow = outp + obase + (long long)r * NN;
#pragma unroll
        for (int j = 0; j < 8; ++j)
            orow[(j << 6) + l] = (A[r][j] >= kth) ? A[r][j] : 0.0f;
    }
}

extern "C" void kernel_launch(void* const* d_in, const int* in_sizes, int n_in,
                              void* d_out, int out_size, void* d_ws, size_t ws_size,
                              hipStream_t stream) {
    const float* x     = (const float*)d_in[0];
    const float* Ws    = (const float*)d_in[1];
    const float* Wphi  = (const float*)d_in[2];
    const float* b_phi = (const float*)d_in[3];
    const float* Wmu   = (const float*)d_in[4];
    const float* b_mu  = (const float*)d_in[5];
    const float* WQ    = (const float*)d_in[6];
    const float* WK    = (const float*)d_in[7];
    float* out = (float*)d_out;

    hipLaunchKernelGGL(k1, dim3(8192), dim3(256), 0, stream,
                       x, Ws, Wphi, b_phi, Wmu, b_mu, WQ, WK);
    hipLaunchKernelGGL(k2f, dim3(1024), dim3(256), 0, stream, out);
}

// Round 10
// 323.997 us; speedup vs baseline: 6.4354x; 6.4354x over previous
//
#include <hip/hip_runtime.h>
#include <math.h>

#define BB 16
#define NN 512
#define TT 32
#define CC 128
#define RR 32
#define DD 64

// numpy npyv(AVX512) einsum contig-two dot emulation:
// 16-lane FMA single accumulator over ascending 16-blocks,
// then the _mm512_reduce_add_ps combine tree. All ops rounding-locked.
__device__ __forceinline__ float dot_np16(const float* __restrict__ a,
                                          const float* __restrict__ b, int n) {
    float lane[16];
#pragma unroll
    for (int l = 0; l < 16; ++l) lane[l] = 0.0f;
    for (int i = 0; i < n; i += 16) {
#pragma unroll
        for (int l = 0; l < 16; ++l)
            lane[l] = __fmaf_rn(a[i + l], b[i + l], lane[l]);
    }
    float m[8], p[4];
#pragma unroll
    for (int i = 0; i < 8; ++i) m[i] = __fadd_rn(lane[i], lane[i + 8]);
#pragma unroll
    for (int i = 0; i < 4; ++i) p[i] = __fadd_rn(m[i], m[i + 4]);
    float q0 = __fadd_rn(p[0], p[2]);
    float q1 = __fadd_rn(p[1], p[3]);
    return __fadd_rn(q0, q1);
}

#define XS 129   // ODD stride: conflict-free for BOTH r-varying and c-varying LDS reads

// ------------- Kernel 1: per-(b,n) pipeline -> Q,K (fp32-faithful) -----------
__global__ __launch_bounds__(256) void k1(const float* __restrict__ x,
        const float* __restrict__ Ws, const float* __restrict__ Wphi,
        const float* __restrict__ b_phi, const float* __restrict__ Wmu,
        const float* __restrict__ b_mu, const float* __restrict__ WQ,
        const float* __restrict__ WK,
        float* __restrict__ gQ, float* __restrict__ gK)
{
    __shared__ float Xs[TT * XS];     // 16.5 KB
    __shared__ float Wss[RR * XS];    // 16.5 KB (staged Ws)
    __shared__ float zta[TT * 33];    // 4.2 KB
    __shared__ float xc[CC];          // avg, later X_c
    __shared__ float wsh[CC];
    __shared__ float zca[RR];
    __shared__ float lg[TT];
    __shared__ float alpha[TT];

    const int tid = threadIdx.x;
    const int bn = blockIdx.x;
    const float* xb = x + (long long)bn * (TT * CC);

    // scalar staging: coalesced global reads, conflict-free LDS stores
#pragma unroll
    for (int k = 0; k < 16; ++k) {
        int i = tid + (k << 8);            // 0..4095
        int t = i >> 7, c = i & 127;
        Xs[t * XS + c]  = xb[i];
        Wss[t * XS + c] = Ws[i];
    }
    __syncthreads();

    // avg = np.mean over t: numpy pairwise 8-accumulator pattern, /32
    if (tid < CC) {
        float r[8];
#pragma unroll
        for (int j = 0; j < 8; ++j) r[j] = Xs[j * XS + tid];
#pragma unroll
        for (int i = 8; i < 32; i += 8)
#pragma unroll
            for (int j = 0; j < 8; ++j) r[j] = __fadd_rn(r[j], Xs[(i + j) * XS + tid]);
        float s = __fadd_rn(__fadd_rn(__fadd_rn(r[0], r[1]), __fadd_rn(r[2], r[3])),
                            __fadd_rn(__fadd_rn(r[4], r[5]), __fadd_rn(r[6], r[7])));
        xc[tid] = s / 32.0f;               // xc holds avg for now
    }
    __syncthreads();

    // z_ca = relu(einsum('c,rc->r', avg, Ws))   [LDS, conflict-free]
    if (tid < RR) {
        const float* wr = &Wss[tid * XS];
        float lane[16];
#pragma unroll
        for (int l = 0; l < 16; ++l) lane[l] = 0.0f;
        for (int i = 0; i < CC; i += 16)
#pragma unroll
            for (int l = 0; l < 16; ++l)
                lane[l] = __fmaf_rn(xc[i + l], wr[i + l], lane[l]);
        float m[8], p[4];
#pragma unroll
        for (int i = 0; i < 8; ++i) m[i] = __fadd_rn(lane[i], lane[i + 8]);
#pragma unroll
        for (int i = 0; i < 4; ++i) p[i] = __fadd_rn(m[i], m[i + 4]);
        float q0 = __fadd_rn(p[0], p[2]), q1 = __fadd_rn(p[1], p[3]);
        zca[tid] = fmaxf(__fadd_rn(q0, q1), 0.0f);
    }
    __syncthreads();

    // w = sigmoid(einsum('r,cr->c', zca, Wphi) + b_phi)
    if (tid < CC) {
        float t = __fadd_rn(dot_np16(zca, Wphi + tid * RR, RR), b_phi[tid]);
        wsh[tid] = 1.0f / (1.0f + expf(-t));
    }
    __syncthreads();

    // z_ta = relu(einsum('tc,rc->tr', X_hat, Ws)), X_hat inlined as
    // __fmul_rn(Xs,wsh) (bitwise identical to materialized X_hat)
#pragma unroll
    for (int k = 0; k < 4; ++k) {
        int i = tid + (k << 8);
        int t = i >> 5, r = i & 31;
        const float* xr = &Xs[t * XS];
        const float* wr = &Wss[r * XS];
        float lane[16];
#pragma unroll
        for (int l = 0; l < 16; ++l) lane[l] = 0.0f;
        for (int c = 0; c < CC; c += 16)
#pragma unroll
            for (int l = 0; l < 16; ++l)
                lane[l] = __fmaf_rn(__fmul_rn(xr[c + l], wsh[c + l]), wr[c + l], lane[l]);
        float m[8], p[4];
#pragma unroll
        for (int i2 = 0; i2 < 8; ++i2) m[i2] = __fadd_rn(lane[i2], lane[i2 + 8]);
#pragma unroll
        for (int i2 = 0; i2 < 4; ++i2) p[i2] = __fadd_rn(m[i2], m[i2 + 4]);
        float q0 = __fadd_rn(p[0], p[2]), q1 = __fadd_rn(p[1], p[3]);
        zta[t * 33 + r] = fmaxf(__fadd_rn(q0, q1), 0.0f);
    }
    __syncthreads();

    // logits
    if (tid < TT) lg[tid] = __fadd_rn(dot_np16(&zta[tid * 33], Wmu, RR), b_mu[0]);
    __syncthreads();

    // softmax over t (max exact; pairwise 8-acc sum like np)
    if (tid == 0) {
        float m = lg[0];
        for (int t = 1; t < TT; ++t) m = fmaxf(m, lg[t]);
        float e[TT];
        for (int t = 0; t < TT; ++t) e[t] = expf(__fsub_rn(lg[t], m));
        float r[8];
#pragma unroll
        for (int j = 0; j < 8; ++j) r[j] = e[j];
#pragma unroll
        for (int i = 8; i < 32; i += 8)
#pragma unroll
            for (int j = 0; j < 8; ++j) r[j] = __fadd_rn(r[j], e[i + j]);
        float s = __fadd_rn(__fadd_rn(__fadd_rn(r[0], r[1]), __fadd_rn(r[2], r[3])),
                            __fadd_rn(__fadd_rn(r[4], r[5]), __fadd_rn(r[6], r[7])));
        for (int t = 0; t < TT; ++t) alpha[t] = e[t] / s;
    }
    __syncthreads();

    // X_c = einsum('t,tc->c', alpha, X_hat): sequential FMA, X_hat inlined
    if (tid < CC) {
        float s = 0.0f;
        for (int t = 0; t < TT; ++t)
            s = __fmaf_rn(alpha[t], __fmul_rn(Xs[t * XS + tid], wsh[tid]), s);
        xc[tid] = s;
    }
    __syncthreads();

    // Q, K projections
    if (tid < 128) {
        int isK = tid >> 6, d = tid & 63;
        const float* Wr = (isK ? WK : WQ) + d * CC;
        float s = dot_np16(xc, Wr, CC);
        if (isK) gK[bn * DD + d] = s;
        else     gQ[bn * DD + d] = s;
    }
}

// ------------- Kernel 2: E rows (np-order fp32) + sigmoid-domain top-8 -------
__device__ __forceinline__ void cxf(float& a, float& b) {
    float mx = fmaxf(a, b), mn = fminf(a, b);
    a = mx; b = mn;
}

__global__ __launch_bounds__(256) void k2f(const float* __restrict__ gQ,
                                           const float* __restrict__ gK,
                                           float* __restrict__ out)
{
    __shared__ float Qs[16][64];
    __shared__ float Kch[64][65];    // one 64-column chunk of the 512-row matrix

    const int tid = threadIdx.x;
    const int gid = blockIdx.x;
    const int dir = gid & 1;
    const int b   = (gid >> 1) & 15;
    const int grp = gid >> 5;                 // 0..31
    const int row_base = grp << 4;

    const float* Qrow = dir ? gK : gQ;        // backward: rows come from K
    const float* Mat  = dir ? gQ : gK;
    float* outp = out + (long long)dir * BB * NN * NN;

    for (int k = 0; k < 4; ++k) {
        int idx = tid + (k << 8);
        Qs[idx >> 6][idx & 63] =
            Qrow[(long long)(b * NN + row_base + (idx >> 6)) * DD + (idx & 63)];
    }

    const int l = tid & 63, w = tid >> 6, wrow = w << 2;
    float A[4][8];

#pragma unroll
    for (int j = 0; j < 8; ++j) {             // 8 column chunks of 64
        __syncthreads();                       // covers Qs on j==0, Kch reuse after
        for (int k = 0; k < 16; ++k) {
            int idx = tid + (k << 8);
            int row = idx >> 6, d = idx & 63;
            Kch[row][d] = Mat[(long long)(b * NN + (j << 6) + row) * DD + d];
        }
        __syncthreads();
#pragma unroll
        for (int r = 0; r < 4; ++r) {
            float e = dot_np16(Qs[wrow + r], Kch[l], DD);
            e = e / 8.0f;                      // scale = sqrt(64), exact
            A[r][j] = 1.0f / (1.0f + expf(-e));  // select in sigmoid domain
        }
    }

    const long long obase = (long long)(b * NN + row_base + wrow) * NN;

#pragma unroll
    for (int r = 0; r < 4; ++r) {
        float L[8];
#pragma unroll
        for (int j = 0; j < 8; ++j) L[j] = A[r][j];

        // Batcher odd-even merge sort, 8 elems, descending
        cxf(L[0],L[1]); cxf(L[2],L[3]); cxf(L[4],L[5]); cxf(L[6],L[7]);
        cxf(L[0],L[2]); cxf(L[1],L[3]); cxf(L[4],L[6]); cxf(L[5],L[7]);
        cxf(L[1],L[2]); cxf(L[5],L[6]);
        cxf(L[0],L[4]); cxf(L[1],L[5]); cxf(L[2],L[6]); cxf(L[3],L[7]);
        cxf(L[2],L[4]); cxf(L[3],L[5]);
        cxf(L[1],L[2]); cxf(L[3],L[4]); cxf(L[5],L[6]);

        // 64-lane butterfly merge: global top-8 of the row in every lane
#pragma unroll
        for (int mask = 1; mask < 64; mask <<= 1) {
            float Pr[8], M[8];
#pragma unroll
            for (int j = 0; j < 8; ++j) Pr[j] = __shfl_xor(L[j], mask, 64);
#pragma unroll
            for (int j = 0; j < 8; ++j) M[j] = fmaxf(L[j], Pr[7 - j]);
            cxf(M[0],M[4]); cxf(M[1],M[5]); cxf(M[2],M[6]); cxf(M[3],M[7]);
            cxf(M[0],M[2]); cxf(M[1],M[3]); cxf(M[4],M[6]); cxf(M[5],M[7]);
            cxf(M[0],M[1]); cxf(M[2],M[3]); cxf(M[4],M[5]); cxf(M[6],M[7]);
#pragma unroll
            for (int j = 0; j < 8; ++j) L[j] = M[j];
        }
        const float kth = L[7];

        float* orow = outp + obase + (long long)r * NN;
#pragma unroll
        for (int j = 0; j < 8; ++j)
            orow[(j << 6) + l] = (A[r][j] >= kth) ? A[r][j] : 0.0f;
    }
}

extern "C" void kernel_launch(void* const* d_in, const int* in_sizes, int n_in,
                              void* d_out, int out_size, void* d_ws, size_t ws_size,
                              hipStream_t stream) {
    const float* x     = (const float*)d_in[0];
    const float* Ws    = (const float*)d_in[1];
    const float* Wphi  = (const float*)d_in[2];
    const float* b_phi = (const float*)d_in[3];
    const float* Wmu   = (const float*)d_in[4];
    const float* b_mu  = (const float*)d_in[5];
    const float* WQ    = (const float*)d_in[6];
    const float* WK    = (const float*)d_in[7];
    float* out = (float*)d_out;

    // Q/K handoff in d_ws (8 MB); fully rewritten by k1 each call -> deterministic.
    float* gQ = (float*)d_ws;
    float* gK = gQ + (long long)BB * NN * DD;

    hipLaunchKernelGGL(k1, dim3(8192), dim3(256), 0, stream,
                       x, Ws, Wphi, b_phi, Wmu, b_mu, WQ, WK, gQ, gK);
    hipLaunchKernelGGL(k2f, dim3(1024), dim3(256), 0, stream, gQ, gK, out);
}

// Round 11
// 196.248 us; speedup vs baseline: 10.6245x; 1.6510x over previous
//
#include <hip/hip_runtime.h>
#include <math.h>

#define BB 16
#define NN 512
#define TT 32
#define CC 128
#define RR 32
#define DD 64

// numpy npyv(AVX512) einsum contig-two dot emulation:
// 16-lane FMA accumulator over ascending 16-blocks + _mm512_reduce_add_ps tree.
// FROZEN CONTRACT: every dot in this file reproduces this exact op sequence.
__device__ __forceinline__ float dot_np16(const float* __restrict__ a,
                                          const float* __restrict__ b, int n) {
    float lane[16];
#pragma unroll
    for (int l = 0; l < 16; ++l) lane[l] = 0.0f;
    for (int i = 0; i < n; i += 16) {
#pragma unroll
        for (int l = 0; l < 16; ++l)
            lane[l] = __fmaf_rn(a[i + l], b[i + l], lane[l]);
    }
    float m[8], p[4];
#pragma unroll
    for (int i = 0; i < 8; ++i) m[i] = __fadd_rn(lane[i], lane[i + 8]);
#pragma unroll
    for (int i = 0; i < 4; ++i) p[i] = __fadd_rn(m[i], m[i + 4]);
    float q0 = __fadd_rn(p[0], p[2]);
    float q1 = __fadd_rn(p[1], p[3]);
    return __fadd_rn(q0, q1);
}

__device__ __forceinline__ float reduce_np16(const float (&lane)[16]) {
    float m[8], p[4];
#pragma unroll
    for (int i = 0; i < 8; ++i) m[i] = __fadd_rn(lane[i], lane[i + 8]);
#pragma unroll
    for (int i = 0; i < 4; ++i) p[i] = __fadd_rn(m[i], m[i + 4]);
    float q0 = __fadd_rn(p[0], p[2]);
    float q1 = __fadd_rn(p[1], p[3]);
    return __fadd_rn(q0, q1);
}

#define XS2 132   // mult of 4: 16B-aligned rows; b128 row-varying reads = uniform 4 words/bank

// ------------- Kernel 1: per-(b,n) pipeline -> Q,K (fp32-faithful) -----------
__global__ __launch_bounds__(256) void k1(const float* __restrict__ x,
        const float* __restrict__ Ws, const float* __restrict__ Wphi,
        const float* __restrict__ b_phi, const float* __restrict__ Wmu,
        const float* __restrict__ b_mu, const float* __restrict__ WQ,
        const float* __restrict__ WK,
        float* __restrict__ gQ, float* __restrict__ gK)
{
    __shared__ float Xs[TT * XS2];    // 16.9 KB  (X, later X_hat in place)
    __shared__ float Wss[RR * XS2];   // 16.9 KB  (staged Ws)
    __shared__ float zta[TT * 33];    // 4.2 KB
    __shared__ float xc[CC];          // avg, later X_c
    __shared__ float wsh[CC];
    __shared__ float zca[RR];
    __shared__ float lg[TT];
    __shared__ float alpha[TT];

    const int tid = threadIdx.x;
    const int bn = blockIdx.x;
    const float* xb = x + (long long)bn * (TT * CC);

    // float4 staging: coalesced global, aligned LDS
#pragma unroll
    for (int k = 0; k < 4; ++k) {
        int idx = tid + (k << 8);          // float4 idx 0..1023
        int t  = idx >> 5;
        int c4 = (idx & 31) << 2;
        *(float4*)&Xs[t * XS2 + c4]  = ((const float4*)xb)[idx];
        *(float4*)&Wss[t * XS2 + c4] = ((const float4*)Ws)[idx];
    }
    __syncthreads();

    // avg = np.mean over t (pairwise 8-acc), /32
    if (tid < CC) {
        float r[8];
#pragma unroll
        for (int j = 0; j < 8; ++j) r[j] = Xs[j * XS2 + tid];
#pragma unroll
        for (int i = 8; i < 32; i += 8)
#pragma unroll
            for (int j = 0; j < 8; ++j) r[j] = __fadd_rn(r[j], Xs[(i + j) * XS2 + tid]);
        float s = __fadd_rn(__fadd_rn(__fadd_rn(r[0], r[1]), __fadd_rn(r[2], r[3])),
                            __fadd_rn(__fadd_rn(r[4], r[5]), __fadd_rn(r[6], r[7])));
        xc[tid] = s / 32.0f;               // xc holds avg
    }
    __syncthreads();

    // z_ca = relu(avg . Ws[r,:]) -- b128 chunks, slot (c&15)+j == dot_np16 order
    if (tid < RR) {
        const float* wr = &Wss[tid * XS2];
        float lane[16];
#pragma unroll
        for (int l = 0; l < 16; ++l) lane[l] = 0.0f;
#pragma unroll
        for (int c = 0; c < CC; c += 4) {
            float4 av = *(const float4*)&xc[c];
            float4 wv = *(const float4*)&wr[c];
            lane[(c & 15) + 0] = __fmaf_rn(av.x, wv.x, lane[(c & 15) + 0]);
            lane[(c & 15) + 1] = __fmaf_rn(av.y, wv.y, lane[(c & 15) + 1]);
            lane[(c & 15) + 2] = __fmaf_rn(av.z, wv.z, lane[(c & 15) + 2]);
            lane[(c & 15) + 3] = __fmaf_rn(av.w, wv.w, lane[(c & 15) + 3]);
        }
        zca[tid] = fmaxf(reduce_np16(lane), 0.0f);
    }
    __syncthreads();

    // w = sigmoid(zca . Wphi[c,:] + b_phi)
    if (tid < CC) {
        float t = __fadd_rn(dot_np16(zca, Wphi + tid * RR, RR), b_phi[tid]);
        wsh[tid] = 1.0f / (1.0f + expf(-t));
    }
    __syncthreads();

    // X_hat in place: Xs <- __fmul_rn(Xs, wsh)  (raw Xs has no readers after this)
#pragma unroll
    for (int k = 0; k < 16; ++k) {
        int i = tid + (k << 8);
        int t = i >> 7, c = i & 127;
        Xs[t * XS2 + c] = __fmul_rn(Xs[t * XS2 + c], wsh[c]);
    }
    __syncthreads();

    // z_ta = relu(X_hat . Ws^T): thread = (t = tid&31, q = tid>>5), r = q+8j.
    // xh float4 read once per chunk, reused for 4 rows (j). Bitwise == dot_np16.
    {
        const int t = tid & 31, q = tid >> 5;
        const float* xr = &Xs[t * XS2];
        float lane[4][16];
#pragma unroll
        for (int j = 0; j < 4; ++j)
#pragma unroll
            for (int l = 0; l < 16; ++l) lane[j][l] = 0.0f;
#pragma unroll
        for (int c = 0; c < CC; c += 4) {
            float4 xv = *(const float4*)&xr[c];
#pragma unroll
            for (int j = 0; j < 4; ++j) {
                float4 wv = *(const float4*)&Wss[(q + 8 * j) * XS2 + c];
                lane[j][(c & 15) + 0] = __fmaf_rn(xv.x, wv.x, lane[j][(c & 15) + 0]);
                lane[j][(c & 15) + 1] = __fmaf_rn(xv.y, wv.y, lane[j][(c & 15) + 1]);
                lane[j][(c & 15) + 2] = __fmaf_rn(xv.z, wv.z, lane[j][(c & 15) + 2]);
                lane[j][(c & 15) + 3] = __fmaf_rn(xv.w, wv.w, lane[j][(c & 15) + 3]);
            }
        }
#pragma unroll
        for (int j = 0; j < 4; ++j)
            zta[t * 33 + q + 8 * j] = fmaxf(reduce_np16(lane[j]), 0.0f);
    }
    __syncthreads();

    // logits
    if (tid < TT) lg[tid] = __fadd_rn(dot_np16(&zta[tid * 33], Wmu, RR), b_mu[0]);
    __syncthreads();

    // softmax over t (max exact; pairwise 8-acc sum like np)
    if (tid == 0) {
        float m = lg[0];
        for (int t = 1; t < TT; ++t) m = fmaxf(m, lg[t]);
        float e[TT];
        for (int t = 0; t < TT; ++t) e[t] = expf(__fsub_rn(lg[t], m));
        float r[8];
#pragma unroll
        for (int j = 0; j < 8; ++j) r[j] = e[j];
#pragma unroll
        for (int i = 8; i < 32; i += 8)
#pragma unroll
            for (int j = 0; j < 8; ++j) r[j] = __fadd_rn(r[j], e[i + j]);
        float s = __fadd_rn(__fadd_rn(__fadd_rn(r[0], r[1]), __fadd_rn(r[2], r[3])),
                            __fadd_rn(__fadd_rn(r[4], r[5]), __fadd_rn(r[6], r[7])));
        for (int t = 0; t < TT; ++t) alpha[t] = e[t] / s;
    }
    __syncthreads();

    // X_c = einsum('t,tc->c', alpha, X_hat): sequential FMA on in-place X_hat
    if (tid < CC) {
        float s = 0.0f;
        for (int t = 0; t < TT; ++t)
            s = __fmaf_rn(alpha[t], Xs[t * XS2 + tid], s);
        xc[tid] = s;
    }
    __syncthreads();

    // Q, K projections
    if (tid < 128) {
        int isK = tid >> 6, d = tid & 63;
        const float* Wr = (isK ? WK : WQ) + d * CC;
        float s = dot_np16(xc, Wr, CC);
        if (isK) gK[bn * DD + d] = s;
        else     gQ[bn * DD + d] = s;
    }
}

// ------------- Kernel 2: E rows (np-order fp32) + sigmoid-domain top-8 -------
__device__ __forceinline__ void cxf(float& a, float& b) {
    float mx = fmaxf(a, b), mn = fminf(a, b);
    a = mx; b = mn;
}

#define KS 68   // Kch row stride: mult of 4 (aligned b128), uniform banks

__global__ __launch_bounds__(256) void k2f(const float* __restrict__ gQ,
                                           const float* __restrict__ gK,
                                           float* __restrict__ out)
{
    __shared__ float Qs[16][64];
    __shared__ float Kch[64 * KS];

    const int tid = threadIdx.x;
    const int gid = blockIdx.x;
    const int dir = gid & 1;
    const int b   = (gid >> 1) & 15;
    const int grp = gid >> 5;                 // 0..31
    const int row_base = grp << 4;

    const float* Qrow = dir ? gK : gQ;        // backward: rows come from K
    const float* Mat  = dir ? gQ : gK;
    float* outp = out + (long long)dir * BB * NN * NN;

    {   // float4 staging of the 16 query rows
        int row = tid >> 4, c4 = (tid & 15) << 2;
        *(float4*)&Qs[row][c4] =
            ((const float4*)Qrow)[(long long)(b * NN + row_base + row) * 16 + (tid & 15)];
    }

    const int l = tid & 63, w = tid >> 6, wrow = w << 2;
    float A[4][8];

#pragma unroll
    for (int j = 0; j < 8; ++j) {             // 8 column chunks of 64
        __syncthreads();                       // covers Qs on j==0, Kch reuse after
#pragma unroll
        for (int k = 0; k < 4; ++k) {          // float4 staging of 64x64 chunk
            int idx = tid + (k << 8);          // 0..1023
            int row = idx >> 4, c4 = (idx & 15) << 2;
            *(float4*)&Kch[row * KS + c4] =
                ((const float4*)Mat)[(long long)(b * NN + (j << 6) + row) * 16 + (idx & 15)];
        }
        __syncthreads();
#pragma unroll
        for (int r = 0; r < 4; ++r) {
            const float* qa = Qs[wrow + r];
            const float* kb = &Kch[l * KS];
            float lane[16];
#pragma unroll
            for (int ll = 0; ll < 16; ++ll) lane[ll] = 0.0f;
#pragma unroll
            for (int c = 0; c < DD; c += 4) {
                float4 qv = *(const float4*)&qa[c];
                float4 kv = *(const float4*)&kb[c];
                lane[(c & 15) + 0] = __fmaf_rn(qv.x, kv.x, lane[(c & 15) + 0]);
                lane[(c & 15) + 1] = __fmaf_rn(qv.y, kv.y, lane[(c & 15) + 1]);
                lane[(c & 15) + 2] = __fmaf_rn(qv.z, kv.z, lane[(c & 15) + 2]);
                lane[(c & 15) + 3] = __fmaf_rn(qv.w, kv.w, lane[(c & 15) + 3]);
            }
            float e = reduce_np16(lane);
            e = e / 8.0f;                      // scale = sqrt(64), exact
            A[r][j] = 1.0f / (1.0f + expf(-e));  // select in sigmoid domain
        }
    }

    const long long obase = (long long)(b * NN + row_base + wrow) * NN;

#pragma unroll
    for (int r = 0; r < 4; ++r) {
        float L[8];
#pragma unroll
        for (int j = 0; j < 8; ++j) L[j] = A[r][j];

        // Batcher odd-even merge sort, 8 elems, descending
        cxf(L[0],L[1]); cxf(L[2],L[3]); cxf(L[4],L[5]); cxf(L[6],L[7]);
        cxf(L[0],L[2]); cxf(L[1],L[3]); cxf(L[4],L[6]); cxf(L[5],L[7]);
        cxf(L[1],L[2]); cxf(L[5],L[6]);
        cxf(L[0],L[4]); cxf(L[1],L[5]); cxf(L[2],L[6]); cxf(L[3],L[7]);
        cxf(L[2],L[4]); cxf(L[3],L[5]);
        cxf(L[1],L[2]); cxf(L[3],L[4]); cxf(L[5],L[6]);

        // 64-lane butterfly merge: global top-8 of the row in every lane
#pragma unroll
        for (int mask = 1; mask < 64; mask <<= 1) {
            float Pr[8], M[8];
#pragma unroll
            for (int j = 0; j < 8; ++j) Pr[j] = __shfl_xor(L[j], mask, 64);
#pragma unroll
            for (int j = 0; j < 8; ++j) M[j] = fmaxf(L[j], Pr[7 - j]);
            cxf(M[0],M[4]); cxf(M[1],M[5]); cxf(M[2],M[6]); cxf(M[3],M[7]);
            cxf(M[0],M[2]); cxf(M[1],M[3]); cxf(M[4],M[6]); cxf(M[5],M[7]);
            cxf(M[0],M[1]); cxf(M[2],M[3]); cxf(M[4],M[5]); cxf(M[6],M[7]);
#pragma unroll
            for (int j = 0; j < 8; ++j) L[j] = M[j];
        }
        const float kth = L[7];

        float* orow = outp + obase + (long long)r * NN;
#pragma unroll
        for (int j = 0; j < 8; ++j)
            orow[(j << 6) + l] = (A[r][j] >= kth) ? A[r][j] : 0.0f;
    }
}

extern "C" void kernel_launch(void* const* d_in, const int* in_sizes, int n_in,
                              void* d_out, int out_size, void* d_ws, size_t ws_size,
                              hipStream_t stream) {
    const float* x     = (const float*)d_in[0];
    const float* Ws    = (const float*)d_in[1];
    const float* Wphi  = (const float*)d_in[2];
    const float* b_phi = (const float*)d_in[3];
    const float* Wmu   = (const float*)d_in[4];
    const float* b_mu  = (const float*)d_in[5];
    const float* WQ    = (const float*)d_in[6];
    const float* WK    = (const float*)d_in[7];
    float* out = (float*)d_out;

    // Q/K handoff in d_ws (8 MB); fully rewritten by k1 each call -> deterministic.
    float* gQ = (float*)d_ws;
    float* gK = gQ + (long long)BB * NN * DD;

    hipLaunchKernelGGL(k1, dim3(8192), dim3(256), 0, stream,
                       x, Ws, Wphi, b_phi, Wmu, b_mu, WQ, WK, gQ, gK);
    hipLaunchKernelGGL(k2f, dim3(1024), dim3(256), 0, stream, gQ, gK, out);
}